// Round 15
// baseline (2652.944 us; speedup 1.0000x reference)
//
#include <hip/hip_runtime.h>

#define NATOMS 300000
#define NCOLS 8
#define VOCABSZ 4096
#define DCOL 32
#define HIDDIM 256
#define NBONDS 320000
#define NGRAPHS 6000
#define NSTEPS 3

constexpr int MP = 300032;             // atoms padded to multiple of 64
constexpr int MTILES64 = MP / 64;      // 4688 gemm blocks

typedef _Float16 f16;
typedef _Float16 f16x4 __attribute__((ext_vector_type(4)));
typedef _Float16 f16x8 __attribute__((ext_vector_type(8)));
typedef float f32x4 __attribute__((ext_vector_type(4)));

// W pre-scaled by 2^7: Wh=fp16(128W), Wl=fp16(128W-Wh) both fp16-NORMAL, so
// all three MFMA cross terms (Ah*Bh, Ah*Bl, Al*Bh) share scale 128 and fold
// into ONE accumulator (r11: verified, absmax 1.95e-3). Single acc = 64 VGPR
// -> occupancy 2->3 blocks/CU, which is the measured BW lever (r13's spill
// kernel sustained 4.17 TB/s at 42% occupancy vs our 1.75 TB/s at 21%).
constexpr float W_SCALE = 128.0f;
constexpr float INV_W   = 1.0f / 128.0f;

// natural hi/lo split for the h state (r11-verified numerics)
__device__ __forceinline__ void split2(float x, f16& h, f16& l) {
    h = (f16)x;
    l = (f16)(x - (float)h);
}

// 16B-unit XOR swizzle (r10: measured ZERO bank conflicts).
__device__ __forceinline__ int swz(int row, int q) {
    return (row * 4 + (q ^ ((row >> 1) & 3))) * 8;
}

// ---------------------------------------------------------------------------
static void* g_pool = nullptr;
__attribute__((constructor)) static void alloc_pool() {
    void* p = nullptr;
    if (hipMalloc(&p, (size_t)1024 * 1024 * 1024) == hipSuccess) {
        hipMemset(p, 0, (size_t)1024 * 1024 * 1024);
        g_pool = p;
    }
}

// ---------------------------------------------------------------------------
__global__ void fill_kernel(float* out, float v, int n) {
    int i = blockIdx.x * blockDim.x + threadIdx.x;
    if (i < n) out[i] = v;
}

// ---------------------------------------------------------------------------
__global__ void build_edges_kernel(const int* __restrict__ bf, int* __restrict__ esrc,
                                   int* __restrict__ nxt, int* head) {
    int e = blockIdx.x * blockDim.x + threadIdx.x;
    if (e >= 2 * NBONDS) return;
    int src, dst;
    if (e < NBONDS) { src = bf[e * 3 + 0]; dst = bf[e * 3 + 1]; }
    else { int i = e - NBONDS; src = bf[i * 3 + 1]; dst = bf[i * 3 + 0]; }
    esrc[e] = src;
    nxt[e] = atomicExch(&head[dst], e);
}

// ---------------------------------------------------------------------------
__global__ void wsplit_kernel(const float* __restrict__ W, f16* __restrict__ Wh,
                              f16* __restrict__ Wl, int n) {
    int i = blockIdx.x * blockDim.x + threadIdx.x;
    if (i >= n) return;
    split2(W[i] * W_SCALE, Wh[i], Wl[i]);
}

__global__ void bsum_kernel(const float* __restrict__ a, const float* __restrict__ b,
                            float* __restrict__ o) {
    int i = threadIdx.x;
    o[i] = a[i] + b[i];
}

// ---------------------------------------------------------------------------
__global__ void embed_kernel(const int* __restrict__ af, const float* __restrict__ emb,
                             f16* __restrict__ xh, f16* __restrict__ xl) {
    int gid = blockIdx.x * blockDim.x + threadIdx.x;
    int i = gid >> 5, k = gid & 31;
    if (i >= NATOMS) return;
    float s = 0.0f;
#pragma unroll
    for (int c = 0; c < NCOLS; c++) {
        int v = af[i * NCOLS + c];
        int idx = v & (VOCABSZ - 1);
        if (v >= 999999999) idx = 0;
        s += emb[((size_t)c * VOCABSZ + idx) * DCOL + k];
    }
    split2(s, xh[(size_t)i * DCOL + k], xl[(size_t)i * DCOL + k]);
}

// ---------------------------------------------------------------------------
__global__ void agg_kernel(const f16* __restrict__ Ahi, const f16* __restrict__ Alo,
                           f16* __restrict__ Ghi, f16* __restrict__ Glo,
                           const int* __restrict__ head, const int* __restrict__ nxt,
                           const int* __restrict__ esrc) {
    int wid = (blockIdx.x * blockDim.x + threadIdx.x) >> 6;
    int lane = threadIdx.x & 63;
    if (wid >= NATOMS) return;
    float4 sh = make_float4(0.f, 0.f, 0.f, 0.f);
    float4 sl = make_float4(0.f, 0.f, 0.f, 0.f);
    int e = head[wid];
    while (e >= 0) {
        int src = esrc[e];
        const f16x4 vh = *(const f16x4*)(Ahi + (size_t)src * HIDDIM + lane * 4);
        const f16x4 vl = *(const f16x4*)(Alo + (size_t)src * HIDDIM + lane * 4);
        sh.x += (float)vh.x; sh.y += (float)vh.y; sh.z += (float)vh.z; sh.w += (float)vh.w;
        sl.x += (float)vl.x; sl.y += (float)vl.y; sl.z += (float)vl.z; sl.w += (float)vl.w;
        e = nxt[e];
    }
    float4 s;
    s.x = sh.x + sl.x; s.y = sh.y + sl.y;
    s.z = sh.z + sl.z; s.w = sh.w + sl.w;
    f16 h0, l0, h1, l1, h2, l2, h3, l3;
    split2(s.x, h0, l0); split2(s.y, h1, l1);
    split2(s.z, h2, l2); split2(s.w, h3, l3);
    f16x4 oh, ol;
    oh.x = h0; oh.y = h1; oh.z = h2; oh.w = h3;
    ol.x = l0; ol.y = l1; ol.z = l2; ol.w = l3;
    *(f16x4*)(Ghi + (size_t)wid * HIDDIM + lane * 4) = oh;
    *(f16x4*)(Glo + (size_t)wid * HIDDIM + lane * 4) = ol;
}

// ---------------------------------------------------------------------------
// MFMA GEMM v6: r12 geometry (64M x 256N block, 4 waves of 64x64, XOR swizzle,
// zero conflicts, minimal traffic) + SINGLE uniform-scale accumulator
// (W x128, r11-verified) + no register prefetch (r12: neutral) ->
// ~125 VGPR/wave -> __launch_bounds__(256,3), 3 blocks/CU (LDS 40KBx3=120KB).
// Theory: concurrency raises achieved HBM BW (r13 spill kernel: 4.17 TB/s at
// 42% occupancy vs our 1.75 TB/s at 21%).
template <bool HAS_A2, bool RELU, int K>
__global__ __launch_bounds__(256, 3) void mfma_gemm(
    const f16* __restrict__ A1h, const f16* __restrict__ A1l,
    const f16* __restrict__ A2h, const f16* __restrict__ A2l,
    const f16* __restrict__ B1h, const f16* __restrict__ B1l,
    const f16* __restrict__ B2h, const f16* __restrict__ B2l,
    const float* __restrict__ bias,
    f16* __restrict__ Chi, f16* __restrict__ Clo) {
    __shared__ __align__(16) f16 sAh[64 * 32];
    __shared__ __align__(16) f16 sAl[64 * 32];
    __shared__ __align__(16) f16 sBh[256 * 32];
    __shared__ __align__(16) f16 sBl[256 * 32];

    const int t = threadIdx.x;
    const int m0 = blockIdx.x * 64;
    const int lane = t & 63;
    const int wid = t >> 6;     // 0..3
    const int wn = wid * 64;    // wave's column origin
    const int quad = lane >> 4;
    const int l16 = lane & 15;
    const int ra = t >> 2;      // staging row
    const int qa = t & 3;       // staging k-quad

    f32x4 acc[4][4];   // [mt][nt] — single accumulator, 64 VGPRs
#pragma unroll
    for (int a = 0; a < 4; a++)
#pragma unroll
        for (int b = 0; b < 4; b++) acc[a][b] = (f32x4){0.f, 0.f, 0.f, 0.f};

    const int NMAT = HAS_A2 ? 2 : 1;
    for (int kb = 0; kb < K; kb += 32) {
        for (int mat = 0; mat < NMAT; mat++) {
            const f16* Ah = (mat == 0) ? A1h : A2h;
            const f16* Al = (mat == 0) ? A1l : A2l;
            const f16* Bh = (mat == 0) ? B1h : B2h;
            const f16* Bl = (mat == 0) ? B1l : B2l;
            __syncthreads();
            {   // stage A: 64 rows x 4 quads
                const int dst = swz(ra & 63, qa);
                const size_t ao = (size_t)(m0 + (ra & 63)) * K + kb + qa * 8;
                *(int4*)(sAh + dst) = *(const int4*)(Ah + ao);
                *(int4*)(sAl + dst) = *(const int4*)(Al + ao);
            }
#pragma unroll
            for (int i = 0; i < 4; i++) {   // stage B: 256 rows x 4 quads
                const int u = t + 256 * i;
                const int r = u >> 2, q = u & 3;
                const int dst = swz(r, q);
                const size_t bo = (size_t)r * K + kb + q * 8;
                *(int4*)(sBh + dst) = *(const int4*)(Bh + bo);
                *(int4*)(sBl + dst) = *(const int4*)(Bl + bo);
            }
            __syncthreads();

            f16x8 fah[4], fal[4];
#pragma unroll
            for (int mt = 0; mt < 4; mt++) {
                const int src = swz(mt * 16 + l16, quad);
                fah[mt] = *(const f16x8*)(sAh + src);
                fal[mt] = *(const f16x8*)(sAl + src);
            }
#pragma unroll
            for (int nt = 0; nt < 4; nt++) {
                const int src = swz(wn + nt * 16 + l16, quad);
                const f16x8 bh = *(const f16x8*)(sBh + src);
                const f16x8 bl = *(const f16x8*)(sBl + src);
#pragma unroll
                for (int mt = 0; mt < 4; mt++) {
                    acc[mt][nt] = __builtin_amdgcn_mfma_f32_16x16x32_f16(fah[mt], bh, acc[mt][nt], 0, 0, 0);
                    acc[mt][nt] = __builtin_amdgcn_mfma_f32_16x16x32_f16(fah[mt], bl, acc[mt][nt], 0, 0, 0);
                    acc[mt][nt] = __builtin_amdgcn_mfma_f32_16x16x32_f16(fal[mt], bh, acc[mt][nt], 0, 0, 0);
                }
            }
        }
    }

#pragma unroll
    for (int mt = 0; mt < 4; mt++) {
#pragma unroll
        for (int nt = 0; nt < 4; nt++) {
            const int col = wn + nt * 16 + l16;
            const float bv = bias[col];
#pragma unroll
            for (int r = 0; r < 4; r++) {
                const int row = m0 + mt * 16 + quad * 4 + r;
                float v = acc[mt][nt][r] * INV_W + bv;
                if (RELU) v = fmaxf(v, 0.f);
                f16 hi, lo;
                split2(v, hi, lo);
                Chi[(size_t)row * HIDDIM + col] = hi;
                Clo[(size_t)row * HIDDIM + col] = lo;
            }
        }
    }
}

// ---------------------------------------------------------------------------
// Segment-mean of final h -> G[6000][256] fp32 (linearity: mean before the
// final linear; r13/r14 verified, absmax improved to 9.77e-4).
__global__ void readout_mean_kernel(const f16* __restrict__ Hhi, const f16* __restrict__ Hlo,
                                    const int* __restrict__ scopes, float* __restrict__ G) {
    int g = blockIdx.x;
    int n = threadIdx.x;
    int start = scopes[g * 2 + 0];
    int len = scopes[g * 2 + 1];
    float s = 0.f;
    for (int j = 0; j < len; j++) {
        size_t o = (size_t)(start + j) * HIDDIM + n;
        s += (float)Hhi[o] + (float)Hlo[o];
    }
    int d = len > 1 ? len : 1;
    G[(size_t)g * HIDDIM + n] = s / (float)d;
}

// ---------------------------------------------------------------------------
// Tiny fp32 GEMM: out[g][n] = G[g][:] . W_out[n][:] + b_out[n], g<6000.
__global__ __launch_bounds__(256) void out_gemm_kernel(
    const float* __restrict__ G, const float* __restrict__ W,
    const float* __restrict__ bias, float* __restrict__ out) {
    __shared__ float sG[16 * 256];
    const int g0 = blockIdx.x * 16;
    const int t = threadIdx.x;
#pragma unroll
    for (int i = 0; i < 16; i++) sG[i * 256 + t] = G[(size_t)(g0 + i) * 256 + t];
    __syncthreads();
    const float bv = bias[t];
    const float* wrow = W + (size_t)t * 256;   // W[n][k] row-major
    float acc[16];
#pragma unroll
    for (int g = 0; g < 16; g++) acc[g] = 0.f;
    for (int k = 0; k < 256; k += 4) {
        const float4 w = *(const float4*)(wrow + k);
#pragma unroll
        for (int g = 0; g < 16; g++) {
            const float4 a = *(const float4*)(sG + g * 256 + k);   // broadcast
            acc[g] = fmaf(a.x, w.x, acc[g]);
            acc[g] = fmaf(a.y, w.y, acc[g]);
            acc[g] = fmaf(a.z, w.z, acc[g]);
            acc[g] = fmaf(a.w, w.w, acc[g]);
        }
    }
#pragma unroll
    for (int g = 0; g < 16; g++) out[(size_t)(g0 + g) * 256 + t] = acc[g] + bv;
}

// ---------------------------------------------------------------------------
extern "C" void kernel_launch(void* const* d_in, const int* in_sizes, int n_in,
                              void* d_out, int out_size, void* d_ws, size_t ws_size,
                              hipStream_t stream) {
    const int* a_features = (const int*)d_in[0];
    const int* b_features = (const int*)d_in[1];
    const int* a_scopes   = (const int*)d_in[2];
    const float* emb      = (const float*)d_in[3];
    const float* W_in     = (const float*)d_in[4];
    const float* b_in     = (const float*)d_in[5];
    const float* W_self   = (const float*)d_in[6];
    const float* b_self   = (const float*)d_in[7];
    const float* W_neigh  = (const float*)d_in[8];
    const float* b_neigh  = (const float*)d_in[9];
    const float* W_out    = (const float*)d_in[10];
    const float* b_out    = (const float*)d_in[11];

    if (g_pool == nullptr) {
        fill_kernel<<<(out_size + 255) / 256, 256, 0, stream>>>(
            (float*)d_out, 77777.0f, out_size);
        return;
    }

    // ---- pool layout (halves) ----
    f16* p = (f16*)g_pool;
    const size_t HB = (size_t)MP * HIDDIM;       // 76,808,192 halves
    f16* hAhi = p;            f16* hAlo = p + HB;
    f16* hBhi = p + 2 * HB;   f16* hBlo = p + 3 * HB;
    f16* hChi = p + 4 * HB;   f16* hClo = p + 5 * HB;
    f16* xhi  = p + 6 * HB;
    f16* xlo  = xhi + (size_t)MP * DCOL;
    f16* Winh = xlo + (size_t)MP * DCOL;
    f16* Winl = Winh + HIDDIM * DCOL;
    f16* Wsh  = Winl + HIDDIM * DCOL;
    f16* Wsl  = Wsh + HIDDIM * HIDDIM;
    f16* Wnh  = Wsl + HIDDIM * HIDDIM;
    f16* Wnl  = Wnh + HIDDIM * HIDDIM;
    float* Gmean = (float*)(Wnl + HIDDIM * HIDDIM);        // [6000][256] fp32
    float* bsum  = Gmean + (size_t)NGRAPHS * HIDDIM;
    int* esrc = (int*)(bsum + HIDDIM);
    int* nxt  = esrc + 2 * NBONDS;
    int* head = nxt + 2 * NBONDS;

    constexpr int NPAD = MP - NATOMS;            // 32 pad rows

    // ---- setup (identical every launch) ----
    hipMemsetAsync(head, 0xFF, (size_t)MP * sizeof(int), stream);
    build_edges_kernel<<<(2 * NBONDS + 255) / 256, 256, 0, stream>>>(b_features, esrc, nxt, head);
    wsplit_kernel<<<(HIDDIM * DCOL + 255) / 256, 256, 0, stream>>>(W_in, Winh, Winl, HIDDIM * DCOL);
    wsplit_kernel<<<(HIDDIM * HIDDIM + 255) / 256, 256, 0, stream>>>(W_self, Wsh, Wsl, HIDDIM * HIDDIM);
    wsplit_kernel<<<(HIDDIM * HIDDIM + 255) / 256, 256, 0, stream>>>(W_neigh, Wnh, Wnl, HIDDIM * HIDDIM);
    bsum_kernel<<<1, HIDDIM, 0, stream>>>(b_self, b_neigh, bsum);

    // Zero padding rows of every pair buffer (pool is persistent).
    constexpr int PADF = NPAD * HIDDIM / 2;      // halves -> floats
    fill_kernel<<<(PADF + 255) / 256, 256, 0, stream>>>((float*)(hAhi + (size_t)NATOMS * HIDDIM), 0.f, PADF);
    fill_kernel<<<(PADF + 255) / 256, 256, 0, stream>>>((float*)(hAlo + (size_t)NATOMS * HIDDIM), 0.f, PADF);
    fill_kernel<<<(PADF + 255) / 256, 256, 0, stream>>>((float*)(hBhi + (size_t)NATOMS * HIDDIM), 0.f, PADF);
    fill_kernel<<<(PADF + 255) / 256, 256, 0, stream>>>((float*)(hBlo + (size_t)NATOMS * HIDDIM), 0.f, PADF);
    fill_kernel<<<(PADF + 255) / 256, 256, 0, stream>>>((float*)(hChi + (size_t)NATOMS * HIDDIM), 0.f, PADF);
    fill_kernel<<<(PADF + 255) / 256, 256, 0, stream>>>((float*)(hClo + (size_t)NATOMS * HIDDIM), 0.f, PADF);
    constexpr int PADX = NPAD * DCOL / 2;
    fill_kernel<<<(PADX + 255) / 256, 256, 0, stream>>>((float*)(xhi + (size_t)NATOMS * DCOL), 0.f, PADX);
    fill_kernel<<<(PADX + 255) / 256, 256, 0, stream>>>((float*)(xlo + (size_t)NATOMS * DCOL), 0.f, PADX);

    // ---- embedding + input linear -> h (pair bufA) ----
    embed_kernel<<<(NATOMS * DCOL + 255) / 256, 256, 0, stream>>>(a_features, emb, xhi, xlo);
    mfma_gemm<false, false, DCOL><<<MTILES64, 256, 0, stream>>>(
        xhi, xlo, nullptr, nullptr, Winh, Winl, nullptr, nullptr, b_in, hAhi, hAlo);

    // ---- 3 message-passing steps with rotating pair buffers ----
    f16 *h_hi = hAhi, *h_lo = hAlo;
    f16 *g_hi = hBhi, *g_lo = hBlo;
    f16 *n_hi = hChi, *n_lo = hClo;
    for (int s = 0; s < NSTEPS; s++) {
        agg_kernel<<<NATOMS / 4, 256, 0, stream>>>(h_hi, h_lo, g_hi, g_lo, head, nxt, esrc);
        mfma_gemm<true, true, HIDDIM><<<MTILES64, 256, 0, stream>>>(
            h_hi, h_lo, g_hi, g_lo, Wsh, Wsl, Wnh, Wnl, bsum, n_hi, n_lo);
        f16* t1 = h_hi; f16* t2 = h_lo;
        h_hi = n_hi; h_lo = n_lo;
        n_hi = g_hi; n_lo = g_lo;
        g_hi = t1;   g_lo = t2;
    }

    // ---- mean first (linearity), then tiny output linear ----
    readout_mean_kernel<<<NGRAPHS, 256, 0, stream>>>(h_hi, h_lo, a_scopes, Gmean);
    out_gemm_kernel<<<NGRAPHS / 16, 256, 0, stream>>>(Gmean, W_out, b_out, (float*)d_out);
}

// Round 16
// 2010.254 us; speedup vs baseline: 1.3197x; 1.3197x over previous
//
#include <hip/hip_runtime.h>

#define NATOMS 300000
#define NCOLS 8
#define VOCABSZ 4096
#define DCOL 32
#define HIDDIM 256
#define NBONDS 320000
#define NGRAPHS 6000
#define NSTEPS 3

constexpr int MP = 300032;             // atoms padded to multiple of 64
constexpr int MTILES64 = MP / 64;      // 4688 gemm blocks
constexpr int HSTR = 2 * HIDDIM;       // interleaved h row: [hi256|lo256]
constexpr int XSTR = 2 * DCOL;         // interleaved x row: [hi32|lo32]

typedef _Float16 f16;
typedef _Float16 f16x8 __attribute__((ext_vector_type(8)));
typedef float f32x4 __attribute__((ext_vector_type(4)));

constexpr float LO_SCALE = 2048.0f;      // 2^11: keeps lo parts fp16-normal
constexpr float INV_LO   = 1.0f / 2048.0f;

__device__ __forceinline__ void split2(float x, f16& h, f16& l) {
    h = (f16)x;
    l = (f16)((x - (float)h) * LO_SCALE);
}

// 16B-unit XOR swizzle (r10: measured ZERO bank conflicts).
__device__ __forceinline__ int swz(int row, int q) {
    return (row * 4 + (q ^ ((row >> 1) & 3))) * 8;
}

// ---------------------------------------------------------------------------
static void* g_pool = nullptr;
__attribute__((constructor)) static void alloc_pool() {
    void* p = nullptr;
    if (hipMalloc(&p, (size_t)1024 * 1024 * 1024) == hipSuccess) {
        hipMemset(p, 0, (size_t)1024 * 1024 * 1024);
        g_pool = p;
    }
}

// ---------------------------------------------------------------------------
__global__ void fill_kernel(float* out, float v, int n) {
    int i = blockIdx.x * blockDim.x + threadIdx.x;
    if (i < n) out[i] = v;
}

// ---------------------------------------------------------------------------
__global__ void build_edges_kernel(const int* __restrict__ bf, int* __restrict__ esrc,
                                   int* __restrict__ nxt, int* head) {
    int e = blockIdx.x * blockDim.x + threadIdx.x;
    if (e >= 2 * NBONDS) return;
    int src, dst;
    if (e < NBONDS) { src = bf[e * 3 + 0]; dst = bf[e * 3 + 1]; }
    else { int i = e - NBONDS; src = bf[i * 3 + 1]; dst = bf[i * 3 + 0]; }
    esrc[e] = src;
    nxt[e] = atomicExch(&head[dst], e);
}

// ---------------------------------------------------------------------------
__global__ void wsplit_kernel(const float* __restrict__ W, f16* __restrict__ Wh,
                              f16* __restrict__ Wl, int n) {
    int i = blockIdx.x * blockDim.x + threadIdx.x;
    if (i >= n) return;
    split2(W[i], Wh[i], Wl[i]);
}

__global__ void bsum_kernel(const float* __restrict__ a, const float* __restrict__ b,
                            float* __restrict__ o) {
    int i = threadIdx.x;
    o[i] = a[i] + b[i];
}

// ---------------------------------------------------------------------------
// Embedding -> interleaved x rows [hi32|lo32].
__global__ void embed_kernel(const int* __restrict__ af, const float* __restrict__ emb,
                             f16* __restrict__ x) {
    int gid = blockIdx.x * blockDim.x + threadIdx.x;
    int i = gid >> 5, k = gid & 31;
    if (i >= NATOMS) return;
    float s = 0.0f;
#pragma unroll
    for (int c = 0; c < NCOLS; c++) {
        int v = af[i * NCOLS + c];
        int idx = v & (VOCABSZ - 1);
        if (v >= 999999999) idx = 0;
        s += emb[((size_t)c * VOCABSZ + idx) * DCOL + k];
    }
    f16 hi, lo;
    split2(s, hi, lo);
    x[(size_t)i * XSTR + k] = hi;
    x[(size_t)i * XSTR + DCOL + k] = lo;
}

// ---------------------------------------------------------------------------
// Aggregation over interleaved rows: ONE f16x8 (16B) per edge per lane covers
// the whole 1KB row (lanes 0..31 carry hi, 32..63 carry scaled-lo). Combine
// hi/lo partials with a single lane^32 butterfly, re-split, write one row.
// vs r14: half the gather instructions, one contiguous line per edge.
__global__ void agg_kernel(const f16* __restrict__ H, f16* __restrict__ G,
                           const int* __restrict__ head, const int* __restrict__ nxt,
                           const int* __restrict__ esrc) {
    int wid = (blockIdx.x * blockDim.x + threadIdx.x) >> 6;
    int lane = threadIdx.x & 63;
    if (wid >= NATOMS) return;
    float a0 = 0.f, a1 = 0.f, a2 = 0.f, a3 = 0.f,
          a4 = 0.f, a5 = 0.f, a6 = 0.f, a7 = 0.f;
    int e = head[wid];
    while (e >= 0) {
        int src = esrc[e];
        const f16x8 v = *(const f16x8*)(H + (size_t)src * HSTR + lane * 8);
        a0 += (float)v[0]; a1 += (float)v[1]; a2 += (float)v[2]; a3 += (float)v[3];
        a4 += (float)v[4]; a5 += (float)v[5]; a6 += (float)v[6]; a7 += (float)v[7];
        e = nxt[e];
    }
    const bool isLo = lane >= 32;
    // bring scaled-lo partials to natural scale, then butterfly-sum with partner
    if (isLo) {
        a0 *= INV_LO; a1 *= INV_LO; a2 *= INV_LO; a3 *= INV_LO;
        a4 *= INV_LO; a5 *= INV_LO; a6 *= INV_LO; a7 *= INV_LO;
    }
    float s0 = a0 + __shfl_xor(a0, 32, 64);
    float s1 = a1 + __shfl_xor(a1, 32, 64);
    float s2 = a2 + __shfl_xor(a2, 32, 64);
    float s3 = a3 + __shfl_xor(a3, 32, 64);
    float s4 = a4 + __shfl_xor(a4, 32, 64);
    float s5 = a5 + __shfl_xor(a5, 32, 64);
    float s6 = a6 + __shfl_xor(a6, 32, 64);
    float s7 = a7 + __shfl_xor(a7, 32, 64);
    // hi-lanes write f16(s); lo-lanes write scaled residual
    f16x8 o;
#define EMIT(J, S)                                                    \
    {                                                                 \
        const f16 hv = (f16)(S);                                      \
        o[J] = isLo ? (f16)(((S) - (float)hv) * LO_SCALE) : hv;       \
    }
    EMIT(0, s0) EMIT(1, s1) EMIT(2, s2) EMIT(3, s3)
    EMIT(4, s4) EMIT(5, s5) EMIT(6, s6) EMIT(7, s7)
#undef EMIT
    *(f16x8*)(G + (size_t)wid * HSTR + lane * 8) = o;
}

// ---------------------------------------------------------------------------
// MFMA GEMM — r14 banked config (363us, zero conflicts, no spills), adapted
// to interleaved A rows [hi_K|lo_K] (stride 2K; lo at +K). B stays separate
// Wh/Wl. __launch_bounds__(256,2) is STRUCTURAL (r13: (256,4) spilled 6 GB;
// r15: 3 blocks/CU doubled FETCH via L3 thrash — do not raise).
template <bool HAS_A2, bool RELU, int K>
__global__ __launch_bounds__(256, 2) void mfma_gemm(
    const f16* __restrict__ A1, const f16* __restrict__ A2,
    const f16* __restrict__ B1h, const f16* __restrict__ B1l,
    const f16* __restrict__ B2h, const f16* __restrict__ B2l,
    const float* __restrict__ bias, f16* __restrict__ C) {
    __shared__ __align__(16) f16 sAh[64 * 32];
    __shared__ __align__(16) f16 sAl[64 * 32];
    __shared__ __align__(16) f16 sBh[256 * 32];
    __shared__ __align__(16) f16 sBl[256 * 32];

    const int t = threadIdx.x;
    const int m0 = blockIdx.x * 64;
    const int lane = t & 63;
    const int wid = t >> 6;     // 0..3
    const int wn = wid * 64;    // wave's column origin
    const int quad = lane >> 4;
    const int l16 = lane & 15;
    const int ra = t >> 2;      // staging row
    const int qa = t & 3;       // staging k-quad

    f32x4 acch[4][4], accl[4][4];   // [mt][nt]
#pragma unroll
    for (int a = 0; a < 4; a++)
#pragma unroll
        for (int b = 0; b < 4; b++) {
            acch[a][b] = (f32x4){0.f, 0.f, 0.f, 0.f};
            accl[a][b] = (f32x4){0.f, 0.f, 0.f, 0.f};
        }

    constexpr int NMAT = HAS_A2 ? 2 : 1;
    constexpr int NST = (K / 32) * NMAT;

    // prefetch registers (named scalars only — r4 lesson: arrays get demoted)
    int4 pAh, pAl, pBh0, pBh1, pBh2, pBh3, pBl0, pBl1, pBl2, pBl3;

#define LOAD_STAGE(S)                                                          \
    {                                                                          \
        const int mat_ = HAS_A2 ? ((S) & 1) : 0;                               \
        const int kb_ = (HAS_A2 ? ((S) >> 1) : (S)) * 32;                      \
        const f16* A_ = (mat_ == 0) ? A1 : A2;                                 \
        const f16* Bh_ = (mat_ == 0) ? B1h : B2h;                              \
        const f16* Bl_ = (mat_ == 0) ? B1l : B2l;                              \
        const size_t ao_ = (size_t)(m0 + ra) * (2 * K) + kb_ + qa * 8;         \
        pAh = *(const int4*)(A_ + ao_);                                        \
        pAl = *(const int4*)(A_ + ao_ + K);                                    \
        const size_t bo_ = (size_t)ra * K + kb_ + qa * 8;                      \
        pBh0 = *(const int4*)(Bh_ + bo_);                                      \
        pBh1 = *(const int4*)(Bh_ + bo_ + (size_t)64 * K);                     \
        pBh2 = *(const int4*)(Bh_ + bo_ + (size_t)128 * K);                    \
        pBh3 = *(const int4*)(Bh_ + bo_ + (size_t)192 * K);                    \
        pBl0 = *(const int4*)(Bl_ + bo_);                                      \
        pBl1 = *(const int4*)(Bl_ + bo_ + (size_t)64 * K);                     \
        pBl2 = *(const int4*)(Bl_ + bo_ + (size_t)128 * K);                    \
        pBl3 = *(const int4*)(Bl_ + bo_ + (size_t)192 * K);                    \
    }

    LOAD_STAGE(0);

    for (int s = 0; s < NST; s++) {
        __syncthreads();
        {
            const int dA = swz(ra, qa);
            *(int4*)(sAh + dA) = pAh;
            *(int4*)(sAl + dA) = pAl;
            const int d0 = swz(ra, qa), d1 = swz(ra + 64, qa);
            const int d2 = swz(ra + 128, qa), d3 = swz(ra + 192, qa);
            *(int4*)(sBh + d0) = pBh0; *(int4*)(sBh + d1) = pBh1;
            *(int4*)(sBh + d2) = pBh2; *(int4*)(sBh + d3) = pBh3;
            *(int4*)(sBl + d0) = pBl0; *(int4*)(sBl + d1) = pBl1;
            *(int4*)(sBl + d2) = pBl2; *(int4*)(sBl + d3) = pBl3;
        }
        __syncthreads();
        if (s + 1 < NST) LOAD_STAGE(s + 1);

        f16x8 fah[4], fal[4];
#pragma unroll
        for (int mt = 0; mt < 4; mt++) {
            const int src = swz(mt * 16 + l16, quad);
            fah[mt] = *(const f16x8*)(sAh + src);
            fal[mt] = *(const f16x8*)(sAl + src);
        }
#pragma unroll
        for (int nt = 0; nt < 4; nt++) {
            const int src = swz(wn + nt * 16 + l16, quad);
            const f16x8 bh = *(const f16x8*)(sBh + src);
            const f16x8 bl = *(const f16x8*)(sBl + src);
#pragma unroll
            for (int mt = 0; mt < 4; mt++) {
                acch[mt][nt] = __builtin_amdgcn_mfma_f32_16x16x32_f16(fah[mt], bh, acch[mt][nt], 0, 0, 0);
                accl[mt][nt] = __builtin_amdgcn_mfma_f32_16x16x32_f16(fah[mt], bl, accl[mt][nt], 0, 0, 0);
                accl[mt][nt] = __builtin_amdgcn_mfma_f32_16x16x32_f16(fal[mt], bh, accl[mt][nt], 0, 0, 0);
            }
        }
    }
#undef LOAD_STAGE

#pragma unroll
    for (int mt = 0; mt < 4; mt++) {
#pragma unroll
        for (int nt = 0; nt < 4; nt++) {
            const int col = wn + nt * 16 + l16;
            const float bv = bias[col];
#pragma unroll
            for (int r = 0; r < 4; r++) {
                const int row = m0 + mt * 16 + quad * 4 + r;
                float v = acch[mt][nt][r] + accl[mt][nt][r] * INV_LO + bv;
                if (RELU) v = fmaxf(v, 0.f);
                f16 hi, lo;
                split2(v, hi, lo);
                C[(size_t)row * HSTR + col] = hi;
                C[(size_t)row * HSTR + HIDDIM + col] = lo;
            }
        }
    }
}

// ---------------------------------------------------------------------------
// Segment-mean of interleaved final h -> G[6000][256] fp32 (linearity:
// mean before the final linear; r13/r14 verified, absmax 9.77e-4).
__global__ void readout_mean_kernel(const f16* __restrict__ H,
                                    const int* __restrict__ scopes, float* __restrict__ G) {
    int g = blockIdx.x;
    int n = threadIdx.x;
    int start = scopes[g * 2 + 0];
    int len = scopes[g * 2 + 1];
    float s = 0.f;
    for (int j = 0; j < len; j++) {
        const f16* row = H + (size_t)(start + j) * HSTR;
        s += (float)row[n] + (float)row[HIDDIM + n] * INV_LO;
    }
    int d = len > 1 ? len : 1;
    G[(size_t)g * HIDDIM + n] = s / (float)d;
}

// ---------------------------------------------------------------------------
// Tiny fp32 GEMM: out[g][n] = G[g][:] . W_out[n][:] + b_out[n], g<6000.
__global__ __launch_bounds__(256) void out_gemm_kernel(
    const float* __restrict__ G, const float* __restrict__ W,
    const float* __restrict__ bias, float* __restrict__ out) {
    __shared__ float sG[16 * 256];
    const int g0 = blockIdx.x * 16;
    const int t = threadIdx.x;
#pragma unroll
    for (int i = 0; i < 16; i++) sG[i * 256 + t] = G[(size_t)(g0 + i) * 256 + t];
    __syncthreads();
    const float bv = bias[t];
    const float* wrow = W + (size_t)t * 256;   // W[n][k] row-major
    float acc[16];
#pragma unroll
    for (int g = 0; g < 16; g++) acc[g] = 0.f;
    for (int k = 0; k < 256; k += 4) {
        const float4 w = *(const float4*)(wrow + k);
#pragma unroll
        for (int g = 0; g < 16; g++) {
            const float4 a = *(const float4*)(sG + g * 256 + k);   // broadcast
            acc[g] = fmaf(a.x, w.x, acc[g]);
            acc[g] = fmaf(a.y, w.y, acc[g]);
            acc[g] = fmaf(a.z, w.z, acc[g]);
            acc[g] = fmaf(a.w, w.w, acc[g]);
        }
    }
#pragma unroll
    for (int g = 0; g < 16; g++) out[(size_t)(g0 + g) * 256 + t] = acc[g] + bv;
}

// ---------------------------------------------------------------------------
extern "C" void kernel_launch(void* const* d_in, const int* in_sizes, int n_in,
                              void* d_out, int out_size, void* d_ws, size_t ws_size,
                              hipStream_t stream) {
    const int* a_features = (const int*)d_in[0];
    const int* b_features = (const int*)d_in[1];
    const int* a_scopes   = (const int*)d_in[2];
    const float* emb      = (const float*)d_in[3];
    const float* W_in     = (const float*)d_in[4];
    const float* b_in     = (const float*)d_in[5];
    const float* W_self   = (const float*)d_in[6];
    const float* b_self   = (const float*)d_in[7];
    const float* W_neigh  = (const float*)d_in[8];
    const float* b_neigh  = (const float*)d_in[9];
    const float* W_out    = (const float*)d_in[10];
    const float* b_out    = (const float*)d_in[11];

    if (g_pool == nullptr) {
        fill_kernel<<<(out_size + 255) / 256, 256, 0, stream>>>(
            (float*)d_out, 77777.0f, out_size);
        return;
    }

    // ---- pool layout (halves); interleaved h buffers [hi256|lo256] ----
    f16* p = (f16*)g_pool;
    const size_t HB2 = (size_t)MP * HSTR;        // 153,616,384 halves / buffer
    f16* bufA = p;
    f16* bufB = p + HB2;
    f16* bufC = p + 2 * HB2;
    f16* xbuf = p + 3 * HB2;                     // [MP][64] interleaved
    f16* Winh = xbuf + (size_t)MP * XSTR;
    f16* Winl = Winh + HIDDIM * DCOL;
    f16* Wsh  = Winl + HIDDIM * DCOL;
    f16* Wsl  = Wsh + HIDDIM * HIDDIM;
    f16* Wnh  = Wsl + HIDDIM * HIDDIM;
    f16* Wnl  = Wnh + HIDDIM * HIDDIM;
    float* Gmean = (float*)(Wnl + HIDDIM * HIDDIM);        // [6000][256] fp32
    float* bsum  = Gmean + (size_t)NGRAPHS * HIDDIM;
    int* esrc = (int*)(bsum + HIDDIM);
    int* nxt  = esrc + 2 * NBONDS;
    int* head = nxt + 2 * NBONDS;

    constexpr int NPAD = MP - NATOMS;            // 32 pad rows

    // ---- setup (identical every launch) ----
    hipMemsetAsync(head, 0xFF, (size_t)MP * sizeof(int), stream);
    build_edges_kernel<<<(2 * NBONDS + 255) / 256, 256, 0, stream>>>(b_features, esrc, nxt, head);
    wsplit_kernel<<<(HIDDIM * DCOL + 255) / 256, 256, 0, stream>>>(W_in, Winh, Winl, HIDDIM * DCOL);
    wsplit_kernel<<<(HIDDIM * HIDDIM + 255) / 256, 256, 0, stream>>>(W_self, Wsh, Wsl, HIDDIM * HIDDIM);
    wsplit_kernel<<<(HIDDIM * HIDDIM + 255) / 256, 256, 0, stream>>>(W_neigh, Wnh, Wnl, HIDDIM * HIDDIM);
    bsum_kernel<<<1, HIDDIM, 0, stream>>>(b_self, b_neigh, bsum);

    // Zero padding rows (pool is persistent; keeps pad lanes deterministic).
    constexpr int PADH = NPAD * HSTR / 2;        // halves -> floats
    fill_kernel<<<(PADH + 255) / 256, 256, 0, stream>>>((float*)(bufA + (size_t)NATOMS * HSTR), 0.f, PADH);
    fill_kernel<<<(PADH + 255) / 256, 256, 0, stream>>>((float*)(bufB + (size_t)NATOMS * HSTR), 0.f, PADH);
    fill_kernel<<<(PADH + 255) / 256, 256, 0, stream>>>((float*)(bufC + (size_t)NATOMS * HSTR), 0.f, PADH);
    constexpr int PADX = NPAD * XSTR / 2;
    fill_kernel<<<(PADX + 255) / 256, 256, 0, stream>>>((float*)(xbuf + (size_t)NATOMS * XSTR), 0.f, PADX);

    // ---- embedding + input linear -> h (bufA) ----
    embed_kernel<<<(NATOMS * DCOL + 255) / 256, 256, 0, stream>>>(a_features, emb, xbuf);
    mfma_gemm<false, false, DCOL><<<MTILES64, 256, 0, stream>>>(
        xbuf, nullptr, Winh, Winl, nullptr, nullptr, b_in, bufA);

    // ---- 3 message-passing steps with rotating buffers ----
    f16* h  = bufA;
    f16* g  = bufB;
    f16* hn = bufC;
    for (int s = 0; s < NSTEPS; s++) {
        agg_kernel<<<NATOMS / 4, 256, 0, stream>>>(h, g, head, nxt, esrc);
        mfma_gemm<true, true, HIDDIM><<<MTILES64, 256, 0, stream>>>(
            h, g, Wsh, Wsl, Wnh, Wnl, bsum, hn);
        f16* old = h;
        h = hn; hn = g; g = old;
    }

    // ---- mean first (linearity), then tiny output linear ----
    readout_mean_kernel<<<NGRAPHS, 256, 0, stream>>>(h, a_scopes, Gmean);
    out_gemm_kernel<<<NGRAPHS / 16, 256, 0, stream>>>(Gmean, W_out, b_out, (float*)d_out);
}